// Round 1
// baseline (9344.543 us; speedup 1.0000x reference)
//
#include <hip/hip_runtime.h>

#define BATCH 512
#define SEQL  512
#define NIN   128
#define NH    512
#define NOUT  128
#define PRED  32
#define NSTEP (SEQL + PRED)

#define G_B 8
#define G_H 32
#define BT  64
#define NWG (G_B * G_H)
#define NTHREADS 256

typedef short bf16x8 __attribute__((ext_vector_type(8)));
typedef float f32x4 __attribute__((ext_vector_type(4)));

#define MFMA __builtin_amdgcn_mfma_f32_16x16x32_bf16

__device__ __forceinline__ unsigned short f2bf(float f) {
    unsigned int u = __float_as_uint(f);
    u = (u + 0x7fffu + ((u >> 16) & 1u)) >> 16;   // RTNE
    return (unsigned short)u;
}
__device__ __forceinline__ float bf2f(unsigned short u) {
    return __uint_as_float(((unsigned int)u) << 16);
}
__device__ __forceinline__ float sigm(float x) {
    x = fminf(fmaxf(x, -30.f), 30.f);
    return 1.f / (1.f + __expf(-x));
}
__device__ __forceinline__ float tanh_f(float x) {
    x = fminf(fmaxf(x, -15.f), 15.f);
    float e = __expf(2.f * x);
    return (e - 1.f) / (e + 1.f);
}

// Persistent GRU kernel.
// WG (bg, hs): batch rows [bg*64, bg*64+64), hidden units [hs*16, hs*16+16).
// LDS (64 KiB exactly): Whh[48][512] bf16 @0, Wih[48][128] bf16 @24576,
//                       Wout[4][512] bf16 @30720. Rows 0..15=r, 16..31=z, 32..47=n.
// XOR swizzle (elem index ^= (row&7)<<3) kills the stride-1KB bank conflict.
__global__ __launch_bounds__(NTHREADS) void gru_kernel(
    const float* __restrict__ z_seq, const float* __restrict__ W_ih,
    const float* __restrict__ W_hh, const float* __restrict__ b_ih,
    const float* __restrict__ b_hh, const float* __restrict__ W_out,
    const float* __restrict__ b_out, float* __restrict__ out,
    unsigned short* __restrict__ hbuf, int* __restrict__ cnt)
{
    __shared__ unsigned short s_w[32768];
    const int tid = threadIdx.x;
    const int wg  = blockIdx.x;
    const int bg  = wg & 7;     // consecutive blockIdx round-robin XCDs -> same bg same XCD
    const int hs  = wg >> 3;

    // ---- stage weight slices (fp32 global -> bf16 LDS, swizzled) ----
    for (int i = tid; i < 48 * 512; i += NTHREADS) {
        int r = i >> 9, k = i & 511;
        int grow = ((r >> 4) << 9) + hs * 16 + (r & 15);   // gate*512 + unit
        s_w[(r << 9) + (k ^ ((r & 7) << 3))] = f2bf(W_hh[grow * 512 + k]);
    }
    for (int i = tid; i < 48 * 128; i += NTHREADS) {
        int r = i >> 7, k = i & 127;
        int grow = ((r >> 4) << 9) + hs * 16 + (r & 15);
        s_w[24576 + (r << 7) + (k ^ ((r & 7) << 3))] = f2bf(W_ih[grow * 128 + k]);
    }
    for (int i = tid; i < 4 * 512; i += NTHREADS) {
        int r = i >> 9, k = i & 511;
        s_w[30720 + (r << 9) + k] = f2bf(W_out[(hs * 4 + r) * 512 + k]);
    }
    __syncthreads();

    const int lane = tid & 63;
    const int wave = tid >> 6;
    const int li   = lane & 15;       // MFMA row-of-A / col-of-B / col-of-C
    const int kq   = lane >> 4;       // k-chunk selector
    const int swz  = (li & 7) << 3;
    const int jg   = hs * 16 + li;    // global hidden unit handled by this lane

    const float bihr = b_ih[jg], bihz = b_ih[NH + jg], bihn = b_ih[2 * NH + jg];
    const float bhhr = b_hh[jg], bhhz = b_hh[NH + jg], bhhn = b_hh[2 * NH + jg];

    const int aRow = bg * BT + wave * 16 + li;        // batch row for A frags
    const int cRow = bg * BT + wave * 16 + kq * 4;    // C rows (+q)
    float hreg[4] = {0.f, 0.f, 0.f, 0.f};             // fp32 h state, lives in regs

    const unsigned short* wB0 = &s_w[(li) << 9];
    const unsigned short* wB1 = &s_w[(16 + li) << 9];
    const unsigned short* wB2 = &s_w[(32 + li) << 9];
    const unsigned short* iB0 = &s_w[24576 + ((li) << 7)];
    const unsigned short* iB1 = &s_w[24576 + ((16 + li) << 7)];
    const unsigned short* iB2 = &s_w[24576 + ((32 + li) << 7)];

    int* myCnt = cnt + bg * 32;   // one counter per batch group, 128B apart

    for (int t = 0; t < NSTEP; ++t) {
        const unsigned short* hin  = hbuf + (t & 1) * (BATCH * NH);
        unsigned short*       hout = hbuf + ((t & 1) ^ 1) * (BATCH * NH);

        // prefetch z_t (encode only) before the hidden matmul to hide HBM latency
        float4 zv0[4], zv1[4];
        if (t < SEQL) {
            const float* zrow = z_seq + ((long)aRow * SEQL + t) * NIN + kq * 8;
#pragma unroll
            for (int ks = 0; ks < 4; ++ks) {
                zv0[ks] = *(const float4*)(zrow + ks * 32);
                zv1[ks] = *(const float4*)(zrow + ks * 32 + 4);
            }
        }

        // A fragments: 16B per lane per k-step, issued up-front for ILP
        const unsigned short* hrow = hin + aRow * NH + kq * 8;
        bf16x8 a[16];
#pragma unroll
        for (int ks = 0; ks < 16; ++ks)
            a[ks] = *(const bf16x8*)(hrow + ks * 32);

        f32x4 hr = {0,0,0,0}, hz = {0,0,0,0}, hn = {0,0,0,0};
#pragma unroll
        for (int ks = 0; ks < 16; ++ks) {
            int so = (ks * 32 + kq * 8) ^ swz;
            hr = MFMA(a[ks], *(const bf16x8*)(wB0 + so), hr, 0, 0, 0);
            hz = MFMA(a[ks], *(const bf16x8*)(wB1 + so), hz, 0, 0, 0);
            hn = MFMA(a[ks], *(const bf16x8*)(wB2 + so), hn, 0, 0, 0);
        }

        f32x4 ir4 = {0,0,0,0}, iz4 = {0,0,0,0}, in4 = {0,0,0,0};
        if (t < SEQL) {
#pragma unroll
            for (int ks = 0; ks < 4; ++ks) {
                union { bf16x8 v; unsigned short u[8]; } az;
                az.u[0] = f2bf(zv0[ks].x); az.u[1] = f2bf(zv0[ks].y);
                az.u[2] = f2bf(zv0[ks].z); az.u[3] = f2bf(zv0[ks].w);
                az.u[4] = f2bf(zv1[ks].x); az.u[5] = f2bf(zv1[ks].y);
                az.u[6] = f2bf(zv1[ks].z); az.u[7] = f2bf(zv1[ks].w);
                int so = (ks * 32 + kq * 8) ^ swz;
                ir4 = MFMA(az.v, *(const bf16x8*)(iB0 + so), ir4, 0, 0, 0);
                iz4 = MFMA(az.v, *(const bf16x8*)(iB1 + so), iz4, 0, 0, 0);
                in4 = MFMA(az.v, *(const bf16x8*)(iB2 + so), in4, 0, 0, 0);
            }
        }

        // gate math (decode: input-side pre-activation is just b_ih since z=0)
#pragma unroll
        for (int q = 0; q < 4; ++q) {
            float r  = sigm(bihr + ir4[q] + bhhr + hr[q]);
            float zz = sigm(bihz + iz4[q] + bhhz + hz[q]);
            float nn = tanh_f(bihn + in4[q] + r * (bhhn + hn[q]));
            float hq = (1.f - zz) * nn + zz * hreg[q];
            hreg[q]  = hq;
            hout[(cRow + q) * NH + jg] = f2bf(hq);
        }

        // per-batch-group barrier (agent-scope); double buffer => one barrier/step
        __syncthreads();
        if (tid == 0) {
            __threadfence();
            __hip_atomic_fetch_add(myCnt, 1, __ATOMIC_ACQ_REL, __HIP_MEMORY_SCOPE_AGENT);
            while (__hip_atomic_load(myCnt, __ATOMIC_ACQUIRE, __HIP_MEMORY_SCOPE_AGENT)
                   < G_H * (t + 1)) { }
        }
        __syncthreads();

        // decode output: y = h_new @ W_out^T + b_out (this WG: 4 output cols)
        if (t >= SEQL) {
            int td = t - SEQL;
            int ob = tid & 3, bl = tid >> 2;
            int brow = bg * BT + bl;
            const unsigned short* hp = hout + brow * NH;
            const unsigned short* wp = &s_w[30720 + (ob << 9)];
            float acc = 0.f;
#pragma unroll 4
            for (int k = 0; k < NH; k += 8) {
                union { uint4 q4; unsigned short u[8]; } hv, wv;
                hv.q4 = *(const uint4*)(hp + k);
                wv.q4 = *(const uint4*)(wp + k);
#pragma unroll
                for (int i = 0; i < 8; ++i)
                    acc += bf2f(hv.u[i]) * bf2f(wv.u[i]);
            }
            out[((long)brow * PRED + td) * NOUT + hs * 4 + ob] = acc + b_out[hs * 4 + ob];
        }
    }
}

extern "C" void kernel_launch(void* const* d_in, const int* in_sizes, int n_in,
                              void* d_out, int out_size, void* d_ws, size_t ws_size,
                              hipStream_t stream)
{
    const float* z_seq = (const float*)d_in[0];
    const float* W_ih  = (const float*)d_in[1];
    const float* W_hh  = (const float*)d_in[2];
    const float* b_ih  = (const float*)d_in[3];
    const float* b_hh  = (const float*)d_in[4];
    const float* W_out = (const float*)d_in[5];
    const float* b_out = (const float*)d_in[6];
    float* out = (float*)d_out;

    unsigned short* hbuf = (unsigned short*)d_ws;                       // 2 x [512][512] bf16
    int* cnt = (int*)((char*)d_ws + (size_t)2 * BATCH * NH * 2);        // barrier counters

    // h0 = 0 and counters = 0, re-done every (captured) call
    hipMemsetAsync(d_ws, 0, (size_t)2 * BATCH * NH * 2 + 4096, stream);

    gru_kernel<<<dim3(NWG), dim3(NTHREADS), 0, stream>>>(
        z_seq, W_ih, W_hh, b_ih, b_hh, W_out, b_out, out, hbuf, cnt);
}

// Round 4
// 3447.057 us; speedup vs baseline: 2.7109x; 2.7109x over previous
//
#include <hip/hip_runtime.h>

#define BATCH 512
#define SEQL  512
#define NIN   128
#define NH    512
#define NOUT  128
#define PRED  32
#define NSTEP (SEQL + PRED)

#define G_B 8
#define G_H 32
#define BT  64
#define NWG (G_B * G_H)
#define NTHREADS 256

typedef short bf16x8 __attribute__((ext_vector_type(8)));
typedef float f32x4 __attribute__((ext_vector_type(4)));
typedef unsigned int u32x4 __attribute__((ext_vector_type(4)));

#define MFMA __builtin_amdgcn_mfma_f32_16x16x32_bf16

__device__ __forceinline__ unsigned short f2bf(float f) {
    unsigned int u = __float_as_uint(f);
    u = (u + 0x7fffu + ((u >> 16) & 1u)) >> 16;   // RTNE
    return (unsigned short)u;
}
__device__ __forceinline__ float sigm(float x) {
    x = fminf(fmaxf(x, -30.f), 30.f);
    return 1.f / (1.f + __expf(-x));
}
__device__ __forceinline__ float tanh_f(float x) {
    x = fminf(fmaxf(x, -15.f), 15.f);
    float e = __expf(2.f * x);
    return (e - 1.f) / (e + 1.f);
}

// Pre-kernel: zero h0 (hbuf[0]) and the barrier counters with sc1 (agent-
// scope) stores, which land at the chip-coherent MALL point where the main
// kernel's sc1 loads / agent atomics read. (hipMemsetAsync may be a blit
// kernel whose plain stores sit dirty in ONE XCD's L2 — invisible to
// MALL-level readers.)
__global__ __launch_bounds__(256) void zero_kernel(unsigned short* hbuf, int* cnt)
{
    const int tid = threadIdx.x, wg = blockIdx.x;
    u32x4 z = {0, 0, 0, 0};
    char* base = (char*)hbuf + ((wg * 256 + tid) * 32);   // 64*256*32B = 512 KiB
    asm volatile("global_store_dwordx4 %0, %1, off sc1" :: "v"(base), "v"(z) : "memory");
    asm volatile("global_store_dwordx4 %0, %1, off offset:16 sc1" :: "v"(base), "v"(z) : "memory");
    if (wg == 0) {
        int zz = 0;
        asm volatile("global_store_dword %0, %1, off sc1" :: "v"(cnt + tid), "v"(zz) : "memory");
    }
}

// Persistent GRU kernel.
// WG (bg, hs): batch rows [bg*64, +64), hidden units [hs*16, +16).
// Sync scheme (placement-independent, fence-free):
//   h data   : sc1 stores/loads  -> complete at the chip-coherent MALL point
//   barrier  : relaxed AGENT-scope returning atomics (execute at same point)
//   ordering : sc1 stores -> s_waitcnt vmcnt(0) -> __syncthreads -> signal;
//              consumer polls via returning RMW, then issues sc1 loads.
// NO buffer_inv / buffer_wbl2 anywhere (that was round 1's 376 GB churn).
// Bounded spin (1M polls) turns any residual deadlock into a fast wrong-
// answer instead of a 600 s timeout.
// LDS (exactly 64 KiB): Whh[48][512] @0, Wih[48][128] @24576, Wout[4][512]
// @30720. XOR swizzle (short idx ^= (row&7)<<3) kills stride-1KB conflicts.
__global__ __launch_bounds__(NTHREADS) void gru_kernel(
    const float* __restrict__ z_seq, const float* __restrict__ W_ih,
    const float* __restrict__ W_hh, const float* __restrict__ b_ih,
    const float* __restrict__ b_hh, const float* __restrict__ W_out,
    const float* __restrict__ b_out, float* __restrict__ out,
    unsigned short* __restrict__ hbuf, int* __restrict__ cnt)
{
    __shared__ unsigned short s_w[32768];
    const int tid = threadIdx.x;
    const int wg  = blockIdx.x;
    const int bg  = wg & 7;
    const int hs  = wg >> 3;

    // ---- stage weight slices (fp32 global -> bf16 LDS, swizzled) ----
    for (int i = tid; i < 48 * 512; i += NTHREADS) {
        int r = i >> 9, k = i & 511;
        int grow = ((r >> 4) << 9) + hs * 16 + (r & 15);   // gate*512 + unit
        s_w[(r << 9) + (k ^ ((r & 7) << 3))] = f2bf(W_hh[grow * 512 + k]);
    }
    for (int i = tid; i < 48 * 128; i += NTHREADS) {
        int r = i >> 7, k = i & 127;
        int grow = ((r >> 4) << 9) + hs * 16 + (r & 15);
        s_w[24576 + (r << 7) + (k ^ ((r & 7) << 3))] = f2bf(W_ih[grow * 128 + k]);
    }
    for (int i = tid; i < 4 * 512; i += NTHREADS) {
        int r = i >> 9, k = i & 511;
        s_w[30720 + (r << 9) + (k ^ ((r & 7) << 3))] = f2bf(W_out[(hs * 4 + r) * 512 + k]);
    }
    __syncthreads();

    const int lane = tid & 63;
    const int wave = tid >> 6;
    const int li   = lane & 15;       // MFMA row-of-A / col-of-B / col-of-C
    const int kq   = lane >> 4;       // k-chunk selector
    const int swz  = (li & 7) << 3;
    const int swzO = (li & 3) << 3;   // Wout has only 4 rows (duplicated cols)
    const int jg   = hs * 16 + li;    // global hidden unit handled by this lane

    const float bihr = b_ih[jg], bihz = b_ih[NH + jg], bihn = b_ih[2 * NH + jg];
    const float bhhr = b_hh[jg], bhhz = b_hh[NH + jg], bhhn = b_hh[2 * NH + jg];
    const float bo   = b_out[hs * 4 + (li & 3)];

    const int aRow = bg * BT + wave * 16 + li;        // batch row for A frags
    const int cRow = bg * BT + wave * 16 + kq * 4;    // C rows (+q)
    float hreg[4] = {0.f, 0.f, 0.f, 0.f};             // fp32 h state in regs

    const unsigned short* wB0 = &s_w[(li) << 9];
    const unsigned short* wB1 = &s_w[(16 + li) << 9];
    const unsigned short* wB2 = &s_w[(32 + li) << 9];
    const unsigned short* iB0 = &s_w[24576 + ((li) << 7)];
    const unsigned short* iB1 = &s_w[24576 + ((16 + li) << 7)];
    const unsigned short* iB2 = &s_w[24576 + ((32 + li) << 7)];
    const unsigned short* oB  = &s_w[30720 + ((li & 3) << 9)];

    int* myCnt = cnt + bg * 32;   // one counter per batch group, 128B apart
    int  dead  = 0;               // set if a barrier times out -> stop waiting

    for (int t = 0; t <= NSTEP; ++t) {
        const unsigned short* hin  = hbuf + (t & 1) * (BATCH * NH);
        unsigned short*       hout = hbuf + ((t & 1) ^ 1) * (BATCH * NH);

        // prefetch z_t (encode only); plain cached loads (read-only data)
        float4 zv0[4], zv1[4];
        if (t < SEQL) {
            const float* zrow = z_seq + ((long)aRow * SEQL + t) * NIN + kq * 8;
#pragma unroll
            for (int ks = 0; ks < 4; ++ks) {
                zv0[ks] = *(const float4*)(zrow + ks * 32);
                zv1[ks] = *(const float4*)(zrow + ks * 32 + 4);
            }
        }

        // A fragments: sc1 = agent-scope load from the MALL coherence point
        const unsigned short* hrow = hin + aRow * NH + kq * 8;
        bf16x8 a[16];
#pragma unroll
        for (int ks = 0; ks < 16; ++ks)
            asm volatile("global_load_dwordx4 %0, %1, off offset:%2 sc1"
                         : "=v"(a[ks]) : "v"(hrow), "i"(ks * 64) : "memory");
        asm volatile("s_waitcnt vmcnt(0)" ::: "memory");
        __builtin_amdgcn_sched_barrier(0);

        // decode output via MFMA on the just-loaded fragments:
        // a[] holds h_t; y_td needs h_{SEQL+1+td} -> emit at t = SEQL+1+td
        if (t > SEQL) {
            int td = t - SEQL - 1;
            f32x4 y4 = {0, 0, 0, 0};
#pragma unroll
            for (int ks = 0; ks < 16; ++ks) {
                int so = (ks * 32 + kq * 8) ^ swzO;
                y4 = MFMA(a[ks], *(const bf16x8*)(oB + so), y4, 0, 0, 0);
            }
            if (li < 4) {
#pragma unroll
                for (int q = 0; q < 4; ++q)
                    out[((long)(cRow + q) * PRED + td) * NOUT + hs * 4 + li] = y4[q] + bo;
            }
        }
        if (t == NSTEP) break;

        f32x4 hr = {0,0,0,0}, hz = {0,0,0,0}, hn = {0,0,0,0};
#pragma unroll
        for (int ks = 0; ks < 16; ++ks) {
            int so = (ks * 32 + kq * 8) ^ swz;
            hr = MFMA(a[ks], *(const bf16x8*)(wB0 + so), hr, 0, 0, 0);
            hz = MFMA(a[ks], *(const bf16x8*)(wB1 + so), hz, 0, 0, 0);
            hn = MFMA(a[ks], *(const bf16x8*)(wB2 + so), hn, 0, 0, 0);
        }

        f32x4 ir4 = {0,0,0,0}, iz4 = {0,0,0,0}, in4 = {0,0,0,0};
        if (t < SEQL) {
#pragma unroll
            for (int ks = 0; ks < 4; ++ks) {
                union { bf16x8 v; unsigned short u[8]; } az;
                az.u[0] = f2bf(zv0[ks].x); az.u[1] = f2bf(zv0[ks].y);
                az.u[2] = f2bf(zv0[ks].z); az.u[3] = f2bf(zv0[ks].w);
                az.u[4] = f2bf(zv1[ks].x); az.u[5] = f2bf(zv1[ks].y);
                az.u[6] = f2bf(zv1[ks].z); az.u[7] = f2bf(zv1[ks].w);
                int so = (ks * 32 + kq * 8) ^ swz;
                ir4 = MFMA(az.v, *(const bf16x8*)(iB0 + so), ir4, 0, 0, 0);
                iz4 = MFMA(az.v, *(const bf16x8*)(iB1 + so), iz4, 0, 0, 0);
                in4 = MFMA(az.v, *(const bf16x8*)(iB2 + so), in4, 0, 0, 0);
            }
        }

        // gate math; h stores go sc1 (straight to the MALL coherence point)
#pragma unroll
        for (int q = 0; q < 4; ++q) {
            float r  = sigm(bihr + ir4[q] + bhhr + hr[q]);
            float zz = sigm(bihz + iz4[q] + bhhz + hz[q]);
            float nn = tanh_f(bihn + in4[q] + r * (bhhn + hn[q]));
            float hq = (1.f - zz) * nn + zz * hreg[q];
            hreg[q]  = hq;
            unsigned short* hp = hout + (cRow + q) * NH + jg;
            int hb = (int)f2bf(hq);
            asm volatile("global_store_short %0, %1, off sc1"
                         :: "v"(hp), "v"(hb) : "memory");
        }

        // ---- per-batch-group barrier, one per step ----
        // sc1 stores complete at MALL (vmcnt retires at coherence point) ->
        // WG-wide sync -> one relaxed agent atomic signal -> per-wave lane-0
        // poll via returning relaxed agent RMW (never cache-served).
        asm volatile("s_waitcnt vmcnt(0)" ::: "memory");
        __syncthreads();
        if (tid == 0)
            __hip_atomic_fetch_add(myCnt, 1, __ATOMIC_RELAXED, __HIP_MEMORY_SCOPE_AGENT);
        const int target = G_H * (t + 1);
        int bail = 0;
        if (!dead && lane == 0) {
            int patience = 1000000;
            while (__hip_atomic_fetch_add(myCnt, 0, __ATOMIC_RELAXED,
                                          __HIP_MEMORY_SCOPE_AGENT) < target) {
                __builtin_amdgcn_s_sleep(1);
                if (--patience == 0) { bail = 1; break; }
            }
        }
        dead |= __builtin_amdgcn_readfirstlane(bail);
        __builtin_amdgcn_sched_barrier(0);
    }
}

extern "C" void kernel_launch(void* const* d_in, const int* in_sizes, int n_in,
                              void* d_out, int out_size, void* d_ws, size_t ws_size,
                              hipStream_t stream)
{
    const float* z_seq = (const float*)d_in[0];
    const float* W_ih  = (const float*)d_in[1];
    const float* W_hh  = (const float*)d_in[2];
    const float* b_ih  = (const float*)d_in[3];
    const float* b_hh  = (const float*)d_in[4];
    const float* W_out = (const float*)d_in[5];
    const float* b_out = (const float*)d_in[6];
    float* out = (float*)d_out;

    unsigned short* hbuf = (unsigned short*)d_ws;                   // 2 x [512][512] bf16
    int* cnt = (int*)((char*)d_ws + (size_t)2 * BATCH * NH * 2);    // barrier counters

    zero_kernel<<<dim3(64), dim3(256), 0, stream>>>(hbuf, cnt);
    gru_kernel<<<dim3(NWG), dim3(NTHREADS), 0, stream>>>(
        z_seq, W_ih, W_hh, b_ih, b_hh, W_out, b_out, out, hbuf, cnt);
}